// Round 20
// baseline (821.023 us; speedup 1.0000x reference)
//
#include <hip/hip_runtime.h>
#include <hip/hip_fp16.h>
#include <cstdint>
#include <cstddef>

#define TT 128
#define HID 256
#define GG4 1024
#define GG3 768

typedef _Float16 f16x2 __attribute__((ext_vector_type(2)));
typedef _Float16 f16x8 __attribute__((ext_vector_type(8)));
typedef short    bf16x8 __attribute__((ext_vector_type(8)));
typedef float    f32x4 __attribute__((ext_vector_type(4)));

union f16x8u { f16x8 v; f16x2 p[4]; uint4 q; };

__device__ __forceinline__ float sigf(float x){ return 1.f/(1.f+__expf(-x)); }
__device__ __forceinline__ float tanh_(float x){
  float cx = fminf(fmaxf(x,-15.f),15.f);
  float e = __expf(2.f*cx);
  return (e-1.f)/(e+1.f);
}

__device__ __forceinline__ float dot2(f16x2 a, f16x2 b, float c){
#if __has_builtin(__builtin_amdgcn_fdot2)
  return __builtin_amdgcn_fdot2(a, b, c, false);
#else
  return c + (float)a[0]*(float)b[0] + (float)a[1]*(float)b[1];
#endif
}

__device__ __forceinline__ ushort f2bf(float x){
  union { float f; uint32_t u; } v; v.f = x;
  uint32_t r = v.u + 0x7FFF + ((v.u >> 16) & 1);
  return (ushort)(r >> 16);
}

// ---------------- fused elementwise prep (6 segments, grid-stride) ----------
__global__ __launch_bounds__(256) void prep_kernel(
    const int* __restrict__ ids, const float* __restrict__ emb, ushort* __restrict__ xh,
    const float* __restrict__ wihf, ushort* __restrict__ wtihf,
    const float* __restrict__ wihb, ushort* __restrict__ wtihb,
    const float* __restrict__ Wiou, ushort* __restrict__ wiouh,
    const float* __restrict__ whhf, const float* __restrict__ whhb,
    _Float16* __restrict__ wtf, _Float16* __restrict__ wtb,
    const float* __restrict__ Uiou, const float* __restrict__ Uf,
    ushort* __restrict__ UTbf)
{
  for (int it = blockIdx.x*256 + threadIdx.x; it < 557056; it += gridDim.x*256) {
    if (it < 327680) {
      int m = it / 40, q = it - m*40;
      int k0 = q << 3;
      int id = ids[m];
      ushort o[8];
#pragma unroll
      for (int j = 0; j < 8; j++) {
        int k = k0 + j;
        o[j] = (k < 300) ? f2bf(emb[(size_t)id*300 + k]) : (ushort)0;
      }
      *(uint4*)&xh[(size_t)m*320 + k0] = *(uint4*)o;
    } else if (it < 409600) {
      int i2 = it - 327680;
      const float* src = wihf; ushort* dst = wtihf;
      if (i2 >= 40960) { i2 -= 40960; src = wihb; dst = wtihb; }
      int r = i2 / 40, q = i2 - r*40;
      int k0 = q << 3;
      ushort o[8];
#pragma unroll
      for (int j = 0; j < 8; j++) {
        int k = k0 + j;
        o[j] = (k < 300) ? f2bf(src[(size_t)r*300 + k]) : (ushort)0;
      }
      *(uint4*)&dst[(size_t)r*320 + k0] = *(uint4*)o;
    } else if (it < 458752) {
      int i2 = it - 409600;
      int r = i2 >> 6, k0 = (i2 & 63) << 3;
      ushort o[8];
#pragma unroll
      for (int j = 0; j < 8; j++) o[j] = f2bf(Wiou[(size_t)r*512 + k0 + j]);
      *(uint4*)&wiouh[(size_t)r*512 + k0] = *(uint4*)o;
    } else if (it < 524288) {
      int i2 = it - 458752;
      int dir = i2 >> 15, rem = i2 & 32767;
      int k8 = rem >> 10, g = rem & 1023;
      const float* w = dir ? whhb : whhf;
      _Float16*   wt = dir ? wtb  : wtf;
      f16x8 pk;
#pragma unroll
      for (int j = 0; j < 8; j++) pk[j] = (_Float16)w[(size_t)g*HID + (k8<<3) + j];
      *(f16x8*)&wt[(((size_t)k8<<10) + g) << 3] = pk;
    } else {
      int i2 = it - 524288;
      int r = i2 >> 5, c = (i2 & 31) << 3;
      const float* src = (r < GG3) ? &Uiou[(size_t)r*HID + c] : &Uf[(size_t)(r-GG3)*HID + c];
      ushort o[8];
#pragma unroll
      for (int j = 0; j < 8; j++) o[j] = f2bf(src[j]);
      *(uint4*)&UTbf[(size_t)r*HID + c] = *(uint4*)o;
    }
  }
}

// ---- fused MFMA bf16 GEMM for BOTH input projections (y<8: fwd, y>=8: bwd) -
__global__ __launch_bounds__(256) void mfma_gemm2_kernel(
    const ushort* __restrict__ A,
    const ushort* __restrict__ Btf, const ushort* __restrict__ Btb,
    const float* __restrict__ bf_, const float* __restrict__ bb_,
    float* __restrict__ Cf, float* __restrict__ Cb, int M, int N, int ksteps)
{
  constexpr int LDS_ROW = 40;
  __shared__ ushort As[128*LDS_ROW];
  __shared__ ushort Bs[128*LDS_ROW];
  const int tid = threadIdx.x;
  const int dirb = blockIdx.y >> 3;
  const ushort* __restrict__ Bt = dirb ? Btb : Btf;
  const float* __restrict__ bias = dirb ? bb_ : bf_;
  float* __restrict__ C = dirb ? Cb : Cf;
  const int m0 = blockIdx.x * 128, n0 = (blockIdx.y & 7) * 128;
  const int wave = tid >> 6, lane = tid & 63;
  const int wm = (wave >> 1) * 64, wn = (wave & 1) * 64;
  const int fr = lane & 15;
  const int fk = (lane >> 4) << 3;
  const size_t Kp = (size_t)ksteps << 5;
  const int r0_ = tid >> 2,        k0_ = (tid & 3) << 3;
  const int r1_ = (tid + 256) >> 2, k1_ = ((tid + 256) & 3) << 3;
  f32x4 acc[4][4] = {};
  {
    const uint4 av0 = *(const uint4*)&A[(size_t)(m0+r0_)*Kp + k0_];
    const uint4 av1 = *(const uint4*)&A[(size_t)(m0+r1_)*Kp + k1_];
    const uint4 bv0 = *(const uint4*)&Bt[(size_t)(n0+r0_)*Kp + k0_];
    const uint4 bv1 = *(const uint4*)&Bt[(size_t)(n0+r1_)*Kp + k1_];
    *(uint4*)&As[r0_*LDS_ROW + k0_] = av0;
    *(uint4*)&As[r1_*LDS_ROW + k1_] = av1;
    *(uint4*)&Bs[r0_*LDS_ROW + k0_] = bv0;
    *(uint4*)&Bs[r1_*LDS_ROW + k1_] = bv1;
  }
  __syncthreads();
  for (int ks = 0; ks < ksteps; ks++) {
    uint4 nav0, nav1, nbv0, nbv1;
    const bool more = (ks + 1 < ksteps);
    if (more) {
      const int kb = (ks + 1) << 5;
      nav0 = *(const uint4*)&A[(size_t)(m0+r0_)*Kp + kb + k0_];
      nav1 = *(const uint4*)&A[(size_t)(m0+r1_)*Kp + kb + k1_];
      nbv0 = *(const uint4*)&Bt[(size_t)(n0+r0_)*Kp + kb + k0_];
      nbv1 = *(const uint4*)&Bt[(size_t)(n0+r1_)*Kp + kb + k1_];
    }
    bf16x8 af[4], bfr[4];
#pragma unroll
    for (int i = 0; i < 4; i++) {
      af[i]  = *(const bf16x8*)&As[(wm + i*16 + fr)*LDS_ROW + fk];
      bfr[i] = *(const bf16x8*)&Bs[(wn + i*16 + fr)*LDS_ROW + fk];
    }
#pragma unroll
    for (int mi = 0; mi < 4; mi++)
#pragma unroll
      for (int ni = 0; ni < 4; ni++)
        acc[mi][ni] = __builtin_amdgcn_mfma_f32_16x16x32_bf16(af[mi], bfr[ni], acc[mi][ni], 0, 0, 0);
    __syncthreads();
    if (more) {
      *(uint4*)&As[r0_*LDS_ROW + k0_] = nav0;
      *(uint4*)&As[r1_*LDS_ROW + k1_] = nav1;
      *(uint4*)&Bs[r0_*LDS_ROW + k0_] = nbv0;
      *(uint4*)&Bs[r1_*LDS_ROW + k1_] = nbv1;
      __syncthreads();
    }
  }
  const int drow = (lane >> 4) << 2, dcol = lane & 15;
#pragma unroll
  for (int mi = 0; mi < 4; mi++) {
#pragma unroll
    for (int ni = 0; ni < 4; ni++) {
      const int col = n0 + wn + ni*16 + dcol;
      const float bv = bias[col];
#pragma unroll
      for (int r = 0; r < 4; r++) {
        const int row = m0 + wm + mi*16 + drow + r;
        C[(size_t)row*N + col] = acc[mi][ni][r] + bv;
      }
    }
  }
}

// ---- iou GEMM with FUSED hx gather: A[n][k] = bf16(concat(hsf,hsb)[tok[n]][k])
__global__ __launch_bounds__(256) void mfma_gemm_iou_kernel(
    const int* __restrict__ tok, const float* __restrict__ hsf,
    const float* __restrict__ hsb, const ushort* __restrict__ Bt,
    float* __restrict__ C, int M, int N, int ksteps)
{
  constexpr int LDS_ROW = 40;
  __shared__ ushort As[128*LDS_ROW];
  __shared__ ushort Bs[128*LDS_ROW];
  const int tid = threadIdx.x;
  const int m0 = blockIdx.x * 128, n0 = blockIdx.y * 128;
  const int wave = tid >> 6, lane = tid & 63;
  const int wm = (wave >> 1) * 64, wn = (wave & 1) * 64;
  const int fr = lane & 15;
  const int fk = (lane >> 4) << 3;
  const size_t Kp = (size_t)ksteps << 5;
  const int r0_ = tid >> 2,        k0_ = (tid & 3) << 3;
  const int r1_ = (tid + 256) >> 2, k1_ = ((tid + 256) & 3) << 3;
  // hoist per-row gather bases
  const int row0 = m0 + r0_, row1 = m0 + r1_;
  const bool v0 = row0 < M, v1 = row1 < M;
  const int tk0 = v0 ? tok[row0] : 0;
  const int tk1 = v1 ? tok[row1] : 0;
  const float* h0f = &hsf[((size_t)(tk0 >> 7)*TT + (tk0 & 127))*HID];
  const float* h0b = &hsb[((size_t)(tk0 >> 7)*TT + (tk0 & 127))*HID];
  const float* h1f = &hsf[((size_t)(tk1 >> 7)*TT + (tk1 & 127))*HID];
  const float* h1b = &hsb[((size_t)(tk1 >> 7)*TT + (tk1 & 127))*HID];
  auto loadA = [&](const float* hf, const float* hbp, bool valid, int kof) -> uint4 {
    uint4 z = make_uint4(0,0,0,0);
    if (!valid) return z;
    const float* s = (kof < 256) ? (hf + kof) : (hbp + kof - 256);
    const float4 f0 = *(const float4*)s;
    const float4 f1 = *(const float4*)(s + 4);
    ushort o[8] = { f2bf(f0.x), f2bf(f0.y), f2bf(f0.z), f2bf(f0.w),
                    f2bf(f1.x), f2bf(f1.y), f2bf(f1.z), f2bf(f1.w) };
    return *(uint4*)o;
  };
  f32x4 acc[4][4] = {};
  {
    const uint4 av0 = loadA(h0f, h0b, v0, k0_);
    const uint4 av1 = loadA(h1f, h1b, v1, k1_);
    const uint4 bv0 = *(const uint4*)&Bt[(size_t)(n0+r0_)*Kp + k0_];
    const uint4 bv1 = *(const uint4*)&Bt[(size_t)(n0+r1_)*Kp + k1_];
    *(uint4*)&As[r0_*LDS_ROW + k0_] = av0;
    *(uint4*)&As[r1_*LDS_ROW + k1_] = av1;
    *(uint4*)&Bs[r0_*LDS_ROW + k0_] = bv0;
    *(uint4*)&Bs[r1_*LDS_ROW + k1_] = bv1;
  }
  __syncthreads();
  for (int ks = 0; ks < ksteps; ks++) {
    uint4 nav0 = make_uint4(0,0,0,0), nav1 = make_uint4(0,0,0,0);
    uint4 nbv0 = make_uint4(0,0,0,0), nbv1 = make_uint4(0,0,0,0);
    const bool more = (ks + 1 < ksteps);
    if (more) {
      const int kb = (ks + 1) << 5;
      nav0 = loadA(h0f, h0b, v0, kb + k0_);
      nav1 = loadA(h1f, h1b, v1, kb + k1_);
      nbv0 = *(const uint4*)&Bt[(size_t)(n0+r0_)*Kp + kb + k0_];
      nbv1 = *(const uint4*)&Bt[(size_t)(n0+r1_)*Kp + kb + k1_];
    }
    bf16x8 af[4], bfr[4];
#pragma unroll
    for (int i = 0; i < 4; i++) {
      af[i]  = *(const bf16x8*)&As[(wm + i*16 + fr)*LDS_ROW + fk];
      bfr[i] = *(const bf16x8*)&Bs[(wn + i*16 + fr)*LDS_ROW + fk];
    }
#pragma unroll
    for (int mi = 0; mi < 4; mi++)
#pragma unroll
      for (int ni = 0; ni < 4; ni++)
        acc[mi][ni] = __builtin_amdgcn_mfma_f32_16x16x32_bf16(af[mi], bfr[ni], acc[mi][ni], 0, 0, 0);
    __syncthreads();
    if (more) {
      *(uint4*)&As[r0_*LDS_ROW + k0_] = nav0;
      *(uint4*)&As[r1_*LDS_ROW + k1_] = nav1;
      *(uint4*)&Bs[r0_*LDS_ROW + k0_] = nbv0;
      *(uint4*)&Bs[r1_*LDS_ROW + k1_] = nbv1;
      __syncthreads();
    }
  }
  const int drow = (lane >> 4) << 2, dcol = lane & 15;
#pragma unroll
  for (int mi = 0; mi < 4; mi++) {
#pragma unroll
    for (int ni = 0; ni < 4; ni++) {
      const int col = n0 + wn + ni*16 + dcol;
#pragma unroll
      for (int r = 0; r < 4; r++) {
        const int row = m0 + wm + mi*16 + drow + r;
        if (row < M) C[(size_t)row*N + col] = acc[mi][ni][r];
      }
    }
  }
}

// -------- LSTM: f16 weights, 9/32 chunks in LDS, x double-buffered ----------
#define RCH 23            // chunks 0..22 from L2; 23..31 in LDS
__global__ __launch_bounds__(512, 2) void lstm_kernel(
    const float* __restrict__ xgf, const float* __restrict__ xgb,
    const _Float16* __restrict__ wtf, const _Float16* __restrict__ wtb,
    const int* __restrict__ lengths,
    float* __restrict__ hsf, float* __restrict__ hsb)
{
  const int b8  = blockIdx.x & 7;
  const int dir = b8 >> 2;
  const int p   = (blockIdx.x >> 3) * 4 + (b8 & 3);   // 0..31
  const int r0 = 2*p, r1 = r0 + 1;
  const float* __restrict__ xg = dir ? xgb : xgf;
  const _Float16* __restrict__ wt = dir ? wtb : wtf;
  float* __restrict__ hs = dir ? hsb : hsf;
  const int t = threadIdx.x;
  const int u = t & 255;

  extern __shared__ char smem[];
  f16x8*    wl  = (f16x8*)smem;                          // [9][2][512] = 147456 B
  _Float16* hb  = (_Float16*)(smem + 147456);            // [2][256]
  float*    exf = (float*)(smem + 147456 + 1024);
  float*    exo = exf + 512;

  uint4 wr0[RCH], wr1[RCH];
#pragma unroll
  for (int c = 0; c < RCH; c++) {
    wr0[c] = *(const uint4*)&wt[(((size_t)c << 10) + t) << 3];
    wr1[c] = *(const uint4*)&wt[(((size_t)c << 10) + t + 512) << 3];
  }
#pragma unroll
  for (int c = RCH; c < 32; c++) {
    wl[((c - RCH)*2 + 0)*512 + t] = *(const f16x8*)&wt[(((size_t)c << 10) + t) << 3];
    wl[((c - RCH)*2 + 1)*512 + t] = *(const f16x8*)&wt[(((size_t)c << 10) + t + 512) << 3];
  }
  if (t < 256) { hb[t] = (_Float16)0.f; hb[256 + t] = (_Float16)0.f; }
  __syncthreads();

  const int len0 = lengths[r0], len1 = lengths[r1];   // len0 >= len1
  float c0 = 0.f, c1 = 0.f;
  // preload x for s=0
  float xa0, xb0, xa1 = 0.f, xb1 = 0.f;
  {
    const int t0 = dir ? (len0 - 1) : 0;
    const float* xr0 = xg + ((size_t)r0*TT + t0)*GG4;
    xa0 = xr0[t]; xb0 = xr0[t + 512];
    if (len1 > 0) {
      const int t1 = dir ? (len1 - 1) : 0;
      const float* xr1 = xg + ((size_t)r1*TT + t1)*GG4;
      xa1 = xr1[t]; xb1 = xr1[t + 512];
    }
  }
  for (int s = 0; s < len0; s++) {
    const bool a1 = s < len1;
    const int t0 = dir ? (len0 - 1 - s) : s;
    const int t1 = dir ? (len1 - 1 - s) : s;
    // issue next step's x loads early (independent of hb)
    float nxa0 = 0.f, nxb0 = 0.f, nxa1 = 0.f, nxb1 = 0.f;
    if (s + 1 < len0) {
      const int nt0 = dir ? (len0 - 2 - s) : (s + 1);
      const float* xr0 = xg + ((size_t)r0*TT + nt0)*GG4;
      nxa0 = xr0[t]; nxb0 = xr0[t + 512];
      if (s + 1 < len1) {
        const int nt1 = dir ? (len1 - 2 - s) : (s + 1);
        const float* xr1 = xg + ((size_t)r1*TT + nt1)*GG4;
        nxa1 = xr1[t]; nxb1 = xr1[t + 512];
      }
    }
    float aa0 = 0.f, aa1 = 0.f, ab0 = 0.f, ab1 = 0.f;
#pragma unroll
    for (int k8 = 0; k8 < 32; k8++) {
      f16x8u w0, w1, h0, h1;
      if (k8 < RCH) { w0.q = wr0[k8]; w1.q = wr1[k8]; }
      else {
        w0.v = wl[((k8 - RCH)*2 + 0)*512 + t];
        w1.v = wl[((k8 - RCH)*2 + 1)*512 + t];
      }
      h0.v = *(const f16x8*)&hb[k8 << 3];
      h1.v = *(const f16x8*)&hb[256 + (k8 << 3)];
#pragma unroll
      for (int j = 0; j < 4; j++) {
        aa0 = dot2(w0.p[j], h0.p[j], aa0);
        aa1 = dot2(w0.p[j], h1.p[j], aa1);
        ab0 = dot2(w1.p[j], h0.p[j], ab0);
        ab1 = dot2(w1.p[j], h1.p[j], ab1);
      }
    }
    if (t >= 256) {
      exf[u]       = aa0 + xa0;  exf[256 + u] = aa1 + xa1;
      exo[u]       = ab0 + xb0;  exo[256 + u] = ab1 + xb1;
    }
    __syncthreads();
    if (t < 256) {
      {
        const float ig = sigf(aa0 + xa0);
        const float gg = tanh_(ab0 + xb0);
        const float fg = sigf(exf[u]);
        const float og = sigf(exo[u]);
        c0 = fg*c0 + ig*gg;
        const float h = og*tanh_(c0);
        hb[u] = (_Float16)h;
        hs[((size_t)r0*TT + t0)*HID + u] = h;
      }
      if (a1) {
        const float ig = sigf(aa1 + xa1);
        const float gg = tanh_(ab1 + xb1);
        const float fg = sigf(exf[256 + u]);
        const float og = sigf(exo[256 + u]);
        c1 = fg*c1 + ig*gg;
        const float h = og*tanh_(c1);
        hb[256 + u] = (_Float16)h;
        hs[((size_t)r1*TT + t1)*HID + u] = h;
      }
    }
    __syncthreads();
    xa0 = nxa0; xb0 = nxb0; xa1 = nxa1; xb1 = nxb1;
  }
}

// ------ merged graph prep: blocks 0..63 = per-tree level sort, 64 = CSR -----
__global__ __launch_bounds__(1024) void graph_kernel(
    const int* __restrict__ lengths, const int* __restrict__ node_level,
    const int* __restrict__ child_idx, const int* __restrict__ parent_idx,
    int* __restrict__ tnlist, int* __restrict__ tlvloff, int* __restrict__ tnlv,
    int* __restrict__ choff, int* __restrict__ chlist,
    int* __restrict__ deg /* zeroed; reused as cursor */, int E, int Nn)
{
  const int tid = threadIdx.x;
  if (blockIdx.x < 64) {
    const int b = blockIdx.x;
    __shared__ int hist[130], cur[129];
    __shared__ int off_s, len_s, mx;
    if (tid == 0) {
      int o = 0;
      for (int i = 0; i < b; i++) o += lengths[i];
      off_s = o; len_s = lengths[b]; mx = 1;
    }
    for (int i = tid; i < 130; i += 1024) hist[i] = 0;
    __syncthreads();
    const int off = off_s, len = len_s;
    for (int i = tid; i < len; i += 1024) {
      int lv = node_level[off + i];
      atomicAdd(&hist[lv], 1);
      atomicMax(&mx, lv + 1);
    }
    __syncthreads();
    if (tid == 0) {
      int s = 0;
      for (int l = 0; l < 129; l++) { cur[l] = s; tlvloff[b*130 + l] = s; s += hist[l]; }
      tlvloff[b*130 + 129] = s;
      tnlv[b] = mx;
    }
    __syncthreads();
    for (int i = tid; i < len; i += 1024) {
      int lv = node_level[off + i];
      int pos = atomicAdd(&cur[lv], 1);
      tnlist[b*128 + pos] = off + i;
    }
  } else {
    __shared__ int part[1024];
    for (int e = tid; e < E; e += 1024) atomicAdd(&deg[parent_idx[e]], 1);
    __syncthreads();
    int loc[8]; int s = 0;
#pragma unroll
    for (int m = 0; m < 8; m++) {
      const int i = tid*8 + m;
      loc[m] = s;
      s += (i < Nn) ? deg[i] : 0;
    }
    part[tid] = s;
    __syncthreads();
    for (int off = 1; off < 1024; off <<= 1) {
      int v = (tid >= off) ? part[tid - off] : 0;
      __syncthreads();
      part[tid] += v;
      __syncthreads();
    }
    const int pre = (tid > 0) ? part[tid-1] : 0;
#pragma unroll
    for (int m = 0; m < 8; m++) {
      const int i = tid*8 + m;
      if (i < Nn) choff[i] = pre + loc[m];
    }
    if (tid == 1023) choff[Nn] = part[1023];
    __syncthreads();
#pragma unroll
    for (int m = 0; m < 8; m++) {
      const int i = tid*8 + m;
      if (i < Nn) deg[i] = pre + loc[m];
    }
    __syncthreads();
    for (int e = tid; e < E; e += 1024) {
      int pos = atomicAdd(&deg[parent_idx[e]], 1);
      chlist[pos] = child_idx[e];
    }
  }
}

// ------- tree: one block/tree; LEVEL-batched phase B (UTbf streamed once) ---
__global__ __launch_bounds__(512) void tree_kernel(
    const int* __restrict__ tnlist, const int* __restrict__ tlvloff,
    const int* __restrict__ tnlv,
    const int* __restrict__ choff, const int* __restrict__ chlist,
    const ushort* __restrict__ UTbf,
    const float* __restrict__ biou, const float* __restrict__ buf_,
    const float* __restrict__ iou,
    float* __restrict__ um, float* __restrict__ fm,
    float* __restrict__ cbuf, float* __restrict__ hout)
{
  const int b = blockIdx.x;
  const int tid = threadIdx.x;
  const int nlv = tnlv[b];
  const int* __restrict__ nl = tnlist + b*128;
  const int* __restrict__ lo = tlvloff + b*130;
  extern __shared__ char tsm[];
  ushort* hl  = (ushort*)tsm;                 // [128][264]
  int*    nid = (int*)(tsm + 128*264*2);      // [128]
  const int j5 = tid >> 5, lane5 = tid & 31;
  const int wave = tid >> 6, lane = tid & 63;
  const int fr16 = lane & 15, khalf = lane >> 4;
  for (int l = 0; l < nlv; l++) {
    const int na = lo[l], ne = lo[l+1];
    const int nL = ne - na;
    const int mT = (nL + 15) >> 4;
    for (int g0 = 0; g0 < (mT << 4); g0 += 16) {
      const int jn = g0 + j5;
      const int n = (jn < nL) ? nl[na + jn] : -1;
      if (lane5 == 0) nid[jn] = n;
      if (n >= 0) {
        f32x4 a[8];
#pragma unroll
        for (int q = 0; q < 8; q++) {
          const int d = (q*32 + lane5) << 2;
          if (d < GG3) a[q] = *(const f32x4*)&iou[(size_t)n*GG3 + d];
          else         a[q] = (f32x4){0.f, 0.f, 0.f, 0.f};
        }
        const int e0 = choff[n], e1 = choff[n+1];
        for (int eb = e0; eb < e1; eb += 4) {
          int ch4[4];
#pragma unroll
          for (int i = 0; i < 4; i++) ch4[i] = (eb + i < e1) ? chlist[eb + i] : -1;
#pragma unroll
          for (int i = 0; i < 4; i++) {
            const int ch = ch4[i];
            if (ch >= 0) {
#pragma unroll
              for (int q = 0; q < 8; q++) {
                const int d = (q*32 + lane5) << 2;
                const f32x4 v = (d < GG3)
                  ? *(const f32x4*)&um[(size_t)ch*GG3 + d]
                  : *(const f32x4*)&fm[(size_t)ch*HID + (d - GG3)];
                a[q] += v;
              }
            }
          }
        }
#pragma unroll
        for (int qq = 0; qq < 2; qq++) {
#pragma unroll
          for (int i = 0; i < 4; i++) {
            const int u = qq*128 + (lane5 << 2) + i;
            const float i_ = a[qq][i]   + biou[u];
            const float o_ = a[qq+2][i] + biou[256 + u];
            const float uu = a[qq+4][i] + biou[512 + u];
            const float cv = sigf(i_)*tanh_(uu) + a[qq+6][i];
            const float hv = sigf(o_)*tanh_(cv);
            cbuf[(size_t)n*HID + u] = cv;
            hl[jn*264 + u] = f2bf(hv);
            hout[(size_t)n*HID + u] = hv;
          }
        }
      } else {
#pragma unroll
        for (int q = 0; q < 8; q++) hl[jn*264 + (q << 5) + lane5] = 0;
      }
    }
    __syncthreads();
    if (l < nlv - 1) {
      for (int nt = wave; nt < 64; nt += 8) {
        bf16x8 bfr[8];
        const int r = nt*16 + fr16;
#pragma unroll
        for (int ks = 0; ks < 8; ks++)
          bfr[ks] = *(const bf16x8*)&UTbf[(size_t)r*HID + ks*32 + (khalf << 3)];
        for (int mt = 0; mt < mT; mt++) {
          f32x4 dacc = {0.f, 0.f, 0.f, 0.f};
#pragma unroll
          for (int ks = 0; ks < 8; ks++) {
            const bf16x8 af = *(const bf16x8*)&hl[(mt*16 + fr16)*264 + ks*32 + (khalf << 3)];
            dacc = __builtin_amdgcn_mfma_f32_16x16x32_bf16(af, bfr[ks], dacc, 0, 0, 0);
          }
          if (r < GG3) {
#pragma unroll
            for (int g = 0; g < 4; g++) {
              const int n2 = nid[mt*16 + (khalf << 2) + g];
              if (n2 >= 0) um[(size_t)n2*GG3 + r] = dacc[g];
            }
          } else {
            const int fr = r - GG3;
            const float bv = buf_[fr];
#pragma unroll
            for (int g = 0; g < 4; g++) {
              const int n2 = nid[mt*16 + (khalf << 2) + g];
              if (n2 >= 0) fm[(size_t)n2*HID + fr] = sigf(dacc[g] + bv) * cbuf[(size_t)n2*HID + fr];
            }
          }
        }
      }
    }
    __syncthreads();
  }
}

// ---------------- launch ------------------------------------------------------
extern "C" void kernel_launch(void* const* d_in, const int* in_sizes, int n_in,
                              void* d_out, int out_size, void* d_ws, size_t ws_size,
                              hipStream_t stream)
{
  const int*   embed_ids = (const int*)d_in[0];
  const int*   lengths   = (const int*)d_in[1];
  const int*   child_idx = (const int*)d_in[2];
  const int*   parent_idx= (const int*)d_in[3];
  const int*   tok_idx   = (const int*)d_in[4];
  const int*   node_level= (const int*)d_in[5];
  const float* emb  = (const float*)d_in[7];
  const float* wihf = (const float*)d_in[8];
  const float* whhf = (const float*)d_in[9];
  const float* bf   = (const float*)d_in[10];
  const float* wihb = (const float*)d_in[11];
  const float* whhb = (const float*)d_in[12];
  const float* bb   = (const float*)d_in[13];
  const float* Wiou = (const float*)d_in[14];
  const float* Uiou = (const float*)d_in[15];
  const float* biou = (const float*)d_in[16];
  const float* Uf   = (const float*)d_in[17];
  const float* buf_ = (const float*)d_in[18];
  const int E  = in_sizes[2];
  const int Nn = in_sizes[4];
  float* hout = (float*)d_out;

  char* w = (char*)d_ws;
  size_t off = 0;
  auto take = [&](size_t bytes) -> char* {
    char* p = w + off;
    off += (bytes + 255) & ~(size_t)255;
    return p;
  };
  int*      deg   = (int*)     take((size_t)(Nn+1)*4);     // zeroed
  size_t zero_end = off;
  ushort*   xh    = (ushort*)  take((size_t)8192*320*2);
  ushort*   wtihf = (ushort*)  take((size_t)1024*320*2);
  ushort*   wtihb = (ushort*)  take((size_t)1024*320*2);
  ushort*   wiouh = (ushort*)  take((size_t)768*512*2);
  float*    xgf   = (float*)   take((size_t)8192*1024*4);
  float*    xgb   = (float*)   take((size_t)8192*1024*4);
  _Float16* wtf   = (_Float16*)take((size_t)32*1024*8*2);
  _Float16* wtb   = (_Float16*)take((size_t)32*1024*8*2);
  float*    hsf   = (float*)   take((size_t)64*128*256*4);
  float*    hsb   = (float*)   take((size_t)64*128*256*4);
  float*    iou   = (float*)   take((size_t)Nn*GG3*4);
  float*    um    = (float*)   take((size_t)Nn*GG3*4);
  float*    fm    = (float*)   take((size_t)Nn*HID*4);
  float*    cbuf  = (float*)   take((size_t)Nn*HID*4);
  ushort*   UTbf  = (ushort*)  take((size_t)1024*256*2);
  int*      tnlist= (int*)     take((size_t)64*128*4);
  int*      tlvloff=(int*)     take((size_t)64*130*4);
  int*      tnlv  = (int*)     take((size_t)64*4);
  int*      choff = (int*)     take((size_t)(Nn+1)*4);
  int*      chlist= (int*)     take((size_t)(E>0?E:1)*4);
  (void)ws_size; (void)n_in; (void)out_size;

  hipMemsetAsync(d_ws, 0, zero_end, stream);
  prep_kernel<<<1024, 256, 0, stream>>>(embed_ids, emb, xh, wihf, wtihf, wihb, wtihb,
                                        Wiou, wiouh, whhf, whhb, wtf, wtb, Uiou, Uf, UTbf);
  mfma_gemm2_kernel<<<dim3(64, 16), 256, 0, stream>>>(xh, wtihf, wtihb, bf, bb, xgf, xgb, 8192, 1024, 10);
  lstm_kernel<<<64, 512, 152576, stream>>>(xgf, xgb, wtf, wtb, lengths, hsf, hsb);
  mfma_gemm_iou_kernel<<<dim3((Nn + 127)/128, 6), 256, 0, stream>>>(tok_idx, hsf, hsb, wiouh, iou, Nn, GG3, 16);
  graph_kernel<<<65, 1024, 0, stream>>>(lengths, node_level, child_idx, parent_idx,
                                        tnlist, tlvloff, tnlv, choff, chlist, deg, E, Nn);
  tree_kernel<<<64, 512, 68096, stream>>>(tnlist, tlvloff, tnlv, choff, chlist, UTbf,
                                          biou, buf_, iou, um, fm, cbuf, hout);
}

// Round 21
// 788.586 us; speedup vs baseline: 1.0411x; 1.0411x over previous
//
#include <hip/hip_runtime.h>
#include <hip/hip_fp16.h>
#include <cstdint>
#include <cstddef>

#define TT 128
#define HID 256
#define GG4 1024
#define GG3 768

typedef _Float16 f16x2 __attribute__((ext_vector_type(2)));
typedef _Float16 f16x8 __attribute__((ext_vector_type(8)));
typedef short    bf16x8 __attribute__((ext_vector_type(8)));
typedef float    f32x4 __attribute__((ext_vector_type(4)));

union f16x8u { f16x8 v; f16x2 p[4]; uint4 q; };

__device__ __forceinline__ float sigf(float x){ return 1.f/(1.f+__expf(-x)); }
__device__ __forceinline__ float tanh_(float x){
  float cx = fminf(fmaxf(x,-15.f),15.f);
  float e = __expf(2.f*cx);
  return (e-1.f)/(e+1.f);
}

__device__ __forceinline__ float dot2(f16x2 a, f16x2 b, float c){
#if __has_builtin(__builtin_amdgcn_fdot2)
  return __builtin_amdgcn_fdot2(a, b, c, false);
#else
  return c + (float)a[0]*(float)b[0] + (float)a[1]*(float)b[1];
#endif
}

__device__ __forceinline__ ushort f2bf(float x){
  union { float f; uint32_t u; } v; v.f = x;
  uint32_t r = v.u + 0x7FFF + ((v.u >> 16) & 1);
  return (ushort)(r >> 16);
}

// ---------------- fused elementwise prep (6 segments, grid-stride) ----------
__global__ __launch_bounds__(256) void prep_kernel(
    const int* __restrict__ ids, const float* __restrict__ emb, ushort* __restrict__ xh,
    const float* __restrict__ wihf, ushort* __restrict__ wtihf,
    const float* __restrict__ wihb, ushort* __restrict__ wtihb,
    const float* __restrict__ Wiou, ushort* __restrict__ wiouh,
    const float* __restrict__ whhf, const float* __restrict__ whhb,
    _Float16* __restrict__ wtf, _Float16* __restrict__ wtb,
    const float* __restrict__ Uiou, const float* __restrict__ Uf,
    ushort* __restrict__ UTbf)
{
  for (int it = blockIdx.x*256 + threadIdx.x; it < 557056; it += gridDim.x*256) {
    if (it < 327680) {
      int m = it / 40, q = it - m*40;
      int k0 = q << 3;
      int id = ids[m];
      ushort o[8];
#pragma unroll
      for (int j = 0; j < 8; j++) {
        int k = k0 + j;
        o[j] = (k < 300) ? f2bf(emb[(size_t)id*300 + k]) : (ushort)0;
      }
      *(uint4*)&xh[(size_t)m*320 + k0] = *(uint4*)o;
    } else if (it < 409600) {
      int i2 = it - 327680;
      const float* src = wihf; ushort* dst = wtihf;
      if (i2 >= 40960) { i2 -= 40960; src = wihb; dst = wtihb; }
      int r = i2 / 40, q = i2 - r*40;
      int k0 = q << 3;
      ushort o[8];
#pragma unroll
      for (int j = 0; j < 8; j++) {
        int k = k0 + j;
        o[j] = (k < 300) ? f2bf(src[(size_t)r*300 + k]) : (ushort)0;
      }
      *(uint4*)&dst[(size_t)r*320 + k0] = *(uint4*)o;
    } else if (it < 458752) {
      int i2 = it - 409600;
      int r = i2 >> 6, k0 = (i2 & 63) << 3;
      ushort o[8];
#pragma unroll
      for (int j = 0; j < 8; j++) o[j] = f2bf(Wiou[(size_t)r*512 + k0 + j]);
      *(uint4*)&wiouh[(size_t)r*512 + k0] = *(uint4*)o;
    } else if (it < 524288) {
      int i2 = it - 458752;
      int dir = i2 >> 15, rem = i2 & 32767;
      int k8 = rem >> 10, g = rem & 1023;
      const float* w = dir ? whhb : whhf;
      _Float16*   wt = dir ? wtb  : wtf;
      f16x8 pk;
#pragma unroll
      for (int j = 0; j < 8; j++) pk[j] = (_Float16)w[(size_t)g*HID + (k8<<3) + j];
      *(f16x8*)&wt[(((size_t)k8<<10) + g) << 3] = pk;
    } else {
      int i2 = it - 524288;
      int r = i2 >> 5, c = (i2 & 31) << 3;
      const float* src = (r < GG3) ? &Uiou[(size_t)r*HID + c] : &Uf[(size_t)(r-GG3)*HID + c];
      ushort o[8];
#pragma unroll
      for (int j = 0; j < 8; j++) o[j] = f2bf(src[j]);
      *(uint4*)&UTbf[(size_t)r*HID + c] = *(uint4*)o;
    }
  }
}

// ---- fused MFMA bf16 GEMM for BOTH input projections (y<8: fwd, y>=8: bwd) -
__global__ __launch_bounds__(256) void mfma_gemm2_kernel(
    const ushort* __restrict__ A,
    const ushort* __restrict__ Btf, const ushort* __restrict__ Btb,
    const float* __restrict__ bf_, const float* __restrict__ bb_,
    float* __restrict__ Cf, float* __restrict__ Cb, int M, int N, int ksteps)
{
  constexpr int LDS_ROW = 40;
  __shared__ ushort As[128*LDS_ROW];
  __shared__ ushort Bs[128*LDS_ROW];
  const int tid = threadIdx.x;
  const int dirb = blockIdx.y >> 3;
  const ushort* __restrict__ Bt = dirb ? Btb : Btf;
  const float* __restrict__ bias = dirb ? bb_ : bf_;
  float* __restrict__ C = dirb ? Cb : Cf;
  const int m0 = blockIdx.x * 128, n0 = (blockIdx.y & 7) * 128;
  const int wave = tid >> 6, lane = tid & 63;
  const int wm = (wave >> 1) * 64, wn = (wave & 1) * 64;
  const int fr = lane & 15;
  const int fk = (lane >> 4) << 3;
  const size_t Kp = (size_t)ksteps << 5;
  const int r0_ = tid >> 2,        k0_ = (tid & 3) << 3;
  const int r1_ = (tid + 256) >> 2, k1_ = ((tid + 256) & 3) << 3;
  f32x4 acc[4][4] = {};
  {
    const uint4 av0 = *(const uint4*)&A[(size_t)(m0+r0_)*Kp + k0_];
    const uint4 av1 = *(const uint4*)&A[(size_t)(m0+r1_)*Kp + k1_];
    const uint4 bv0 = *(const uint4*)&Bt[(size_t)(n0+r0_)*Kp + k0_];
    const uint4 bv1 = *(const uint4*)&Bt[(size_t)(n0+r1_)*Kp + k1_];
    *(uint4*)&As[r0_*LDS_ROW + k0_] = av0;
    *(uint4*)&As[r1_*LDS_ROW + k1_] = av1;
    *(uint4*)&Bs[r0_*LDS_ROW + k0_] = bv0;
    *(uint4*)&Bs[r1_*LDS_ROW + k1_] = bv1;
  }
  __syncthreads();
  for (int ks = 0; ks < ksteps; ks++) {
    uint4 nav0, nav1, nbv0, nbv1;
    const bool more = (ks + 1 < ksteps);
    if (more) {
      const int kb = (ks + 1) << 5;
      nav0 = *(const uint4*)&A[(size_t)(m0+r0_)*Kp + kb + k0_];
      nav1 = *(const uint4*)&A[(size_t)(m0+r1_)*Kp + kb + k1_];
      nbv0 = *(const uint4*)&Bt[(size_t)(n0+r0_)*Kp + kb + k0_];
      nbv1 = *(const uint4*)&Bt[(size_t)(n0+r1_)*Kp + kb + k1_];
    }
    bf16x8 af[4], bfr[4];
#pragma unroll
    for (int i = 0; i < 4; i++) {
      af[i]  = *(const bf16x8*)&As[(wm + i*16 + fr)*LDS_ROW + fk];
      bfr[i] = *(const bf16x8*)&Bs[(wn + i*16 + fr)*LDS_ROW + fk];
    }
#pragma unroll
    for (int mi = 0; mi < 4; mi++)
#pragma unroll
      for (int ni = 0; ni < 4; ni++)
        acc[mi][ni] = __builtin_amdgcn_mfma_f32_16x16x32_bf16(af[mi], bfr[ni], acc[mi][ni], 0, 0, 0);
    __syncthreads();
    if (more) {
      *(uint4*)&As[r0_*LDS_ROW + k0_] = nav0;
      *(uint4*)&As[r1_*LDS_ROW + k1_] = nav1;
      *(uint4*)&Bs[r0_*LDS_ROW + k0_] = nbv0;
      *(uint4*)&Bs[r1_*LDS_ROW + k1_] = nbv1;
      __syncthreads();
    }
  }
  const int drow = (lane >> 4) << 2, dcol = lane & 15;
#pragma unroll
  for (int mi = 0; mi < 4; mi++) {
#pragma unroll
    for (int ni = 0; ni < 4; ni++) {
      const int col = n0 + wn + ni*16 + dcol;
      const float bv = bias[col];
#pragma unroll
      for (int r = 0; r < 4; r++) {
        const int row = m0 + wm + mi*16 + drow + r;
        C[(size_t)row*N + col] = acc[mi][ni][r] + bv;
      }
    }
  }
}

// ---- iou GEMM with FUSED hx gather: A[n][k] = bf16(concat(hsf,hsb)[tok[n]][k])
__global__ __launch_bounds__(256) void mfma_gemm_iou_kernel(
    const int* __restrict__ tok, const float* __restrict__ hsf,
    const float* __restrict__ hsb, const ushort* __restrict__ Bt,
    float* __restrict__ C, int M, int N, int ksteps)
{
  constexpr int LDS_ROW = 40;
  __shared__ ushort As[128*LDS_ROW];
  __shared__ ushort Bs[128*LDS_ROW];
  const int tid = threadIdx.x;
  const int m0 = blockIdx.x * 128, n0 = blockIdx.y * 128;
  const int wave = tid >> 6, lane = tid & 63;
  const int wm = (wave >> 1) * 64, wn = (wave & 1) * 64;
  const int fr = lane & 15;
  const int fk = (lane >> 4) << 3;
  const size_t Kp = (size_t)ksteps << 5;
  const int r0_ = tid >> 2,        k0_ = (tid & 3) << 3;
  const int r1_ = (tid + 256) >> 2, k1_ = ((tid + 256) & 3) << 3;
  const int row0 = m0 + r0_, row1 = m0 + r1_;
  const bool v0 = row0 < M, v1 = row1 < M;
  const int tk0 = v0 ? tok[row0] : 0;
  const int tk1 = v1 ? tok[row1] : 0;
  const float* h0f = &hsf[((size_t)(tk0 >> 7)*TT + (tk0 & 127))*HID];
  const float* h0b = &hsb[((size_t)(tk0 >> 7)*TT + (tk0 & 127))*HID];
  const float* h1f = &hsf[((size_t)(tk1 >> 7)*TT + (tk1 & 127))*HID];
  const float* h1b = &hsb[((size_t)(tk1 >> 7)*TT + (tk1 & 127))*HID];
  auto loadA = [&](const float* hf, const float* hbp, bool valid, int kof) -> uint4 {
    uint4 z = make_uint4(0,0,0,0);
    if (!valid) return z;
    const float* s = (kof < 256) ? (hf + kof) : (hbp + kof - 256);
    const float4 f0 = *(const float4*)s;
    const float4 f1 = *(const float4*)(s + 4);
    ushort o[8] = { f2bf(f0.x), f2bf(f0.y), f2bf(f0.z), f2bf(f0.w),
                    f2bf(f1.x), f2bf(f1.y), f2bf(f1.z), f2bf(f1.w) };
    return *(uint4*)o;
  };
  f32x4 acc[4][4] = {};
  {
    const uint4 av0 = loadA(h0f, h0b, v0, k0_);
    const uint4 av1 = loadA(h1f, h1b, v1, k1_);
    const uint4 bv0 = *(const uint4*)&Bt[(size_t)(n0+r0_)*Kp + k0_];
    const uint4 bv1 = *(const uint4*)&Bt[(size_t)(n0+r1_)*Kp + k1_];
    *(uint4*)&As[r0_*LDS_ROW + k0_] = av0;
    *(uint4*)&As[r1_*LDS_ROW + k1_] = av1;
    *(uint4*)&Bs[r0_*LDS_ROW + k0_] = bv0;
    *(uint4*)&Bs[r1_*LDS_ROW + k1_] = bv1;
  }
  __syncthreads();
  for (int ks = 0; ks < ksteps; ks++) {
    uint4 nav0 = make_uint4(0,0,0,0), nav1 = make_uint4(0,0,0,0);
    uint4 nbv0 = make_uint4(0,0,0,0), nbv1 = make_uint4(0,0,0,0);
    const bool more = (ks + 1 < ksteps);
    if (more) {
      const int kb = (ks + 1) << 5;
      nav0 = loadA(h0f, h0b, v0, kb + k0_);
      nav1 = loadA(h1f, h1b, v1, kb + k1_);
      nbv0 = *(const uint4*)&Bt[(size_t)(n0+r0_)*Kp + kb + k0_];
      nbv1 = *(const uint4*)&Bt[(size_t)(n0+r1_)*Kp + kb + k1_];
    }
    bf16x8 af[4], bfr[4];
#pragma unroll
    for (int i = 0; i < 4; i++) {
      af[i]  = *(const bf16x8*)&As[(wm + i*16 + fr)*LDS_ROW + fk];
      bfr[i] = *(const bf16x8*)&Bs[(wn + i*16 + fr)*LDS_ROW + fk];
    }
#pragma unroll
    for (int mi = 0; mi < 4; mi++)
#pragma unroll
      for (int ni = 0; ni < 4; ni++)
        acc[mi][ni] = __builtin_amdgcn_mfma_f32_16x16x32_bf16(af[mi], bfr[ni], acc[mi][ni], 0, 0, 0);
    __syncthreads();
    if (more) {
      *(uint4*)&As[r0_*LDS_ROW + k0_] = nav0;
      *(uint4*)&As[r1_*LDS_ROW + k1_] = nav1;
      *(uint4*)&Bs[r0_*LDS_ROW + k0_] = nbv0;
      *(uint4*)&Bs[r1_*LDS_ROW + k1_] = nbv1;
      __syncthreads();
    }
  }
  const int drow = (lane >> 4) << 2, dcol = lane & 15;
#pragma unroll
  for (int mi = 0; mi < 4; mi++) {
#pragma unroll
    for (int ni = 0; ni < 4; ni++) {
      const int col = n0 + wn + ni*16 + dcol;
#pragma unroll
      for (int r = 0; r < 4; r++) {
        const int row = m0 + wm + mi*16 + drow + r;
        if (row < M) C[(size_t)row*N + col] = acc[mi][ni][r];
      }
    }
  }
}

// -------- LSTM: f16 weights, 9/32 chunks in LDS (round-19 proven form) ------
#define RCH 23            // chunks 0..22 from L2; 23..31 in LDS
__global__ __launch_bounds__(512, 2) void lstm_kernel(
    const float* __restrict__ xgf, const float* __restrict__ xgb,
    const _Float16* __restrict__ wtf, const _Float16* __restrict__ wtb,
    const int* __restrict__ lengths,
    float* __restrict__ hsf, float* __restrict__ hsb)
{
  const int b8  = blockIdx.x & 7;
  const int dir = b8 >> 2;
  const int p   = (blockIdx.x >> 3) * 4 + (b8 & 3);   // 0..31
  const int r0 = 2*p, r1 = r0 + 1;
  const float* __restrict__ xg = dir ? xgb : xgf;
  const _Float16* __restrict__ wt = dir ? wtb : wtf;
  float* __restrict__ hs = dir ? hsb : hsf;
  const int t = threadIdx.x;
  const int u = t & 255;

  extern __shared__ char smem[];
  f16x8*    wl  = (f16x8*)smem;                          // [9][2][512] = 147456 B
  _Float16* hb  = (_Float16*)(smem + 147456);            // [2][256]
  float*    exf = (float*)(smem + 147456 + 1024);
  float*    exo = exf + 512;

  uint4 wr0[RCH], wr1[RCH];
#pragma unroll
  for (int c = 0; c < RCH; c++) {
    wr0[c] = *(const uint4*)&wt[(((size_t)c << 10) + t) << 3];
    wr1[c] = *(const uint4*)&wt[(((size_t)c << 10) + t + 512) << 3];
  }
#pragma unroll
  for (int c = RCH; c < 32; c++) {
    wl[((c - RCH)*2 + 0)*512 + t] = *(const f16x8*)&wt[(((size_t)c << 10) + t) << 3];
    wl[((c - RCH)*2 + 1)*512 + t] = *(const f16x8*)&wt[(((size_t)c << 10) + t + 512) << 3];
  }
  if (t < 256) { hb[t] = (_Float16)0.f; hb[256 + t] = (_Float16)0.f; }
  __syncthreads();

  const int len0 = lengths[r0], len1 = lengths[r1];   // len0 >= len1
  float c0 = 0.f, c1 = 0.f;
  for (int s = 0; s < len0; s++) {
    const bool a1 = s < len1;
    const int t0 = dir ? (len0 - 1 - s) : s;
    const int t1 = dir ? (len1 - 1 - s) : s;
    const float* xr0 = xg + ((size_t)r0*TT + t0)*GG4;
    const float xa0 = xr0[t], xb0 = xr0[t + 512];
    float xa1 = 0.f, xb1 = 0.f;
    if (a1) {
      const float* xr1 = xg + ((size_t)r1*TT + t1)*GG4;
      xa1 = xr1[t]; xb1 = xr1[t + 512];
    }
    float aa0 = 0.f, aa1 = 0.f, ab0 = 0.f, ab1 = 0.f;
#pragma unroll
    for (int k8 = 0; k8 < 32; k8++) {
      f16x8u w0, w1, h0, h1;
      if (k8 < RCH) { w0.q = wr0[k8]; w1.q = wr1[k8]; }
      else {
        w0.v = wl[((k8 - RCH)*2 + 0)*512 + t];
        w1.v = wl[((k8 - RCH)*2 + 1)*512 + t];
      }
      h0.v = *(const f16x8*)&hb[k8 << 3];
      h1.v = *(const f16x8*)&hb[256 + (k8 << 3)];
#pragma unroll
      for (int j = 0; j < 4; j++) {
        aa0 = dot2(w0.p[j], h0.p[j], aa0);
        aa1 = dot2(w0.p[j], h1.p[j], aa1);
        ab0 = dot2(w1.p[j], h0.p[j], ab0);
        ab1 = dot2(w1.p[j], h1.p[j], ab1);
      }
    }
    if (t >= 256) {
      exf[u]       = aa0 + xa0;  exf[256 + u] = aa1 + xa1;
      exo[u]       = ab0 + xb0;  exo[256 + u] = ab1 + xb1;
    }
    __syncthreads();
    if (t < 256) {
      {
        const float ig = sigf(aa0 + xa0);
        const float gg = tanh_(ab0 + xb0);
        const float fg = sigf(exf[u]);
        const float og = sigf(exo[u]);
        c0 = fg*c0 + ig*gg;
        const float h = og*tanh_(c0);
        hb[u] = (_Float16)h;
        hs[((size_t)r0*TT + t0)*HID + u] = h;
      }
      if (a1) {
        const float ig = sigf(aa1 + xa1);
        const float gg = tanh_(ab1 + xb1);
        const float fg = sigf(exf[256 + u]);
        const float og = sigf(exo[256 + u]);
        c1 = fg*c1 + ig*gg;
        const float h = og*tanh_(c1);
        hb[256 + u] = (_Float16)h;
        hs[((size_t)r1*TT + t1)*HID + u] = h;
      }
    }
    __syncthreads();
  }
}

// ------ merged graph prep: blocks 0..63 = per-tree level sort, 64 = CSR -----
__global__ __launch_bounds__(1024) void graph_kernel(
    const int* __restrict__ lengths, const int* __restrict__ node_level,
    const int* __restrict__ child_idx, const int* __restrict__ parent_idx,
    int* __restrict__ tnlist, int* __restrict__ tlvloff, int* __restrict__ tnlv,
    int* __restrict__ choff, int* __restrict__ chlist,
    int* __restrict__ deg /* zeroed; reused as cursor */, int E, int Nn)
{
  const int tid = threadIdx.x;
  if (blockIdx.x < 64) {
    const int b = blockIdx.x;
    __shared__ int hist[130], cur[129];
    __shared__ int off_s, len_s, mx;
    if (tid == 0) {
      int o = 0;
      for (int i = 0; i < b; i++) o += lengths[i];
      off_s = o; len_s = lengths[b]; mx = 1;
    }
    for (int i = tid; i < 130; i += 1024) hist[i] = 0;
    __syncthreads();
    const int off = off_s, len = len_s;
    for (int i = tid; i < len; i += 1024) {
      int lv = node_level[off + i];
      atomicAdd(&hist[lv], 1);
      atomicMax(&mx, lv + 1);
    }
    __syncthreads();
    if (tid == 0) {
      int s = 0;
      for (int l = 0; l < 129; l++) { cur[l] = s; tlvloff[b*130 + l] = s; s += hist[l]; }
      tlvloff[b*130 + 129] = s;
      tnlv[b] = mx;
    }
    __syncthreads();
    for (int i = tid; i < len; i += 1024) {
      int lv = node_level[off + i];
      int pos = atomicAdd(&cur[lv], 1);
      tnlist[b*128 + pos] = off + i;
    }
  } else {
    __shared__ int part[1024];
    for (int e = tid; e < E; e += 1024) atomicAdd(&deg[parent_idx[e]], 1);
    __syncthreads();
    int loc[8]; int s = 0;
#pragma unroll
    for (int m = 0; m < 8; m++) {
      const int i = tid*8 + m;
      loc[m] = s;
      s += (i < Nn) ? deg[i] : 0;
    }
    part[tid] = s;
    __syncthreads();
    for (int off = 1; off < 1024; off <<= 1) {
      int v = (tid >= off) ? part[tid - off] : 0;
      __syncthreads();
      part[tid] += v;
      __syncthreads();
    }
    const int pre = (tid > 0) ? part[tid-1] : 0;
#pragma unroll
    for (int m = 0; m < 8; m++) {
      const int i = tid*8 + m;
      if (i < Nn) choff[i] = pre + loc[m];
    }
    if (tid == 1023) choff[Nn] = part[1023];
    __syncthreads();
#pragma unroll
    for (int m = 0; m < 8; m++) {
      const int i = tid*8 + m;
      if (i < Nn) deg[i] = pre + loc[m];
    }
    __syncthreads();
    for (int e = tid; e < E; e += 1024) {
      int pos = atomicAdd(&deg[parent_idx[e]], 1);
      chlist[pos] = child_idx[e];
    }
  }
}

// ------- tree: one block/tree; LEVEL-batched phase B (UTbf streamed once) ---
__global__ __launch_bounds__(512) void tree_kernel(
    const int* __restrict__ tnlist, const int* __restrict__ tlvloff,
    const int* __restrict__ tnlv,
    const int* __restrict__ choff, const int* __restrict__ chlist,
    const ushort* __restrict__ UTbf,
    const float* __restrict__ biou, const float* __restrict__ buf_,
    const float* __restrict__ iou,
    float* __restrict__ um, float* __restrict__ fm,
    float* __restrict__ cbuf, float* __restrict__ hout)
{
  const int b = blockIdx.x;
  const int tid = threadIdx.x;
  const int nlv = tnlv[b];
  const int* __restrict__ nl = tnlist + b*128;
  const int* __restrict__ lo = tlvloff + b*130;
  extern __shared__ char tsm[];
  ushort* hl  = (ushort*)tsm;                 // [128][264]
  int*    nid = (int*)(tsm + 128*264*2);      // [128]
  const int j5 = tid >> 5, lane5 = tid & 31;
  const int wave = tid >> 6, lane = tid & 63;
  const int fr16 = lane & 15, khalf = lane >> 4;
  for (int l = 0; l < nlv; l++) {
    const int na = lo[l], ne = lo[l+1];
    const int nL = ne - na;
    const int mT = (nL + 15) >> 4;
    for (int g0 = 0; g0 < (mT << 4); g0 += 16) {
      const int jn = g0 + j5;
      const int n = (jn < nL) ? nl[na + jn] : -1;
      if (lane5 == 0) nid[jn] = n;
      if (n >= 0) {
        f32x4 a[8];
#pragma unroll
        for (int q = 0; q < 8; q++) {
          const int d = (q*32 + lane5) << 2;
          if (d < GG3) a[q] = *(const f32x4*)&iou[(size_t)n*GG3 + d];
          else         a[q] = (f32x4){0.f, 0.f, 0.f, 0.f};
        }
        const int e0 = choff[n], e1 = choff[n+1];
        for (int eb = e0; eb < e1; eb += 4) {
          int ch4[4];
#pragma unroll
          for (int i = 0; i < 4; i++) ch4[i] = (eb + i < e1) ? chlist[eb + i] : -1;
#pragma unroll
          for (int i = 0; i < 4; i++) {
            const int ch = ch4[i];
            if (ch >= 0) {
#pragma unroll
              for (int q = 0; q < 8; q++) {
                const int d = (q*32 + lane5) << 2;
                const f32x4 v = (d < GG3)
                  ? *(const f32x4*)&um[(size_t)ch*GG3 + d]
                  : *(const f32x4*)&fm[(size_t)ch*HID + (d - GG3)];
                a[q] += v;
              }
            }
          }
        }
#pragma unroll
        for (int qq = 0; qq < 2; qq++) {
#pragma unroll
          for (int i = 0; i < 4; i++) {
            const int u = qq*128 + (lane5 << 2) + i;
            const float i_ = a[qq][i]   + biou[u];
            const float o_ = a[qq+2][i] + biou[256 + u];
            const float uu = a[qq+4][i] + biou[512 + u];
            const float cv = sigf(i_)*tanh_(uu) + a[qq+6][i];
            const float hv = sigf(o_)*tanh_(cv);
            cbuf[(size_t)n*HID + u] = cv;
            hl[jn*264 + u] = f2bf(hv);
            hout[(size_t)n*HID + u] = hv;
          }
        }
      } else {
#pragma unroll
        for (int q = 0; q < 8; q++) hl[jn*264 + (q << 5) + lane5] = 0;
      }
    }
    __syncthreads();
    if (l < nlv - 1) {
      for (int nt = wave; nt < 64; nt += 8) {
        bf16x8 bfr[8];
        const int r = nt*16 + fr16;
#pragma unroll
        for (int ks = 0; ks < 8; ks++)
          bfr[ks] = *(const bf16x8*)&UTbf[(size_t)r*HID + ks*32 + (khalf << 3)];
        for (int mt = 0; mt < mT; mt++) {
          f32x4 dacc = {0.f, 0.f, 0.f, 0.f};
#pragma unroll
          for (int ks = 0; ks < 8; ks++) {
            const bf16x8 af = *(const bf16x8*)&hl[(mt*16 + fr16)*264 + ks*32 + (khalf << 3)];
            dacc = __builtin_amdgcn_mfma_f32_16x16x32_bf16(af, bfr[ks], dacc, 0, 0, 0);
          }
          if (r < GG3) {
#pragma unroll
            for (int g = 0; g < 4; g++) {
              const int n2 = nid[mt*16 + (khalf << 2) + g];
              if (n2 >= 0) um[(size_t)n2*GG3 + r] = dacc[g];
            }
          } else {
            const int fr = r - GG3;
            const float bv = buf_[fr];
#pragma unroll
            for (int g = 0; g < 4; g++) {
              const int n2 = nid[mt*16 + (khalf << 2) + g];
              if (n2 >= 0) fm[(size_t)n2*HID + fr] = sigf(dacc[g] + bv) * cbuf[(size_t)n2*HID + fr];
            }
          }
        }
      }
    }
    __syncthreads();
  }
}

// ---------------- launch ------------------------------------------------------
extern "C" void kernel_launch(void* const* d_in, const int* in_sizes, int n_in,
                              void* d_out, int out_size, void* d_ws, size_t ws_size,
                              hipStream_t stream)
{
  const int*   embed_ids = (const int*)d_in[0];
  const int*   lengths   = (const int*)d_in[1];
  const int*   child_idx = (const int*)d_in[2];
  const int*   parent_idx= (const int*)d_in[3];
  const int*   tok_idx   = (const int*)d_in[4];
  const int*   node_level= (const int*)d_in[5];
  const float* emb  = (const float*)d_in[7];
  const float* wihf = (const float*)d_in[8];
  const float* whhf = (const float*)d_in[9];
  const float* bf   = (const float*)d_in[10];
  const float* wihb = (const float*)d_in[11];
  const float* whhb = (const float*)d_in[12];
  const float* bb   = (const float*)d_in[13];
  const float* Wiou = (const float*)d_in[14];
  const float* Uiou = (const float*)d_in[15];
  const float* biou = (const float*)d_in[16];
  const float* Uf   = (const float*)d_in[17];
  const float* buf_ = (const float*)d_in[18];
  const int E  = in_sizes[2];
  const int Nn = in_sizes[4];
  float* hout = (float*)d_out;

  char* w = (char*)d_ws;
  size_t off = 0;
  auto take = [&](size_t bytes) -> char* {
    char* p = w + off;
    off += (bytes + 255) & ~(size_t)255;
    return p;
  };
  int*      deg   = (int*)     take((size_t)(Nn+1)*4);     // zeroed
  size_t zero_end = off;
  ushort*   xh    = (ushort*)  take((size_t)8192*320*2);
  ushort*   wtihf = (ushort*)  take((size_t)1024*320*2);
  ushort*   wtihb = (ushort*)  take((size_t)1024*320*2);
  ushort*   wiouh = (ushort*)  take((size_t)768*512*2);
  float*    xgf   = (float*)   take((size_t)8192*1024*4);
  float*    xgb   = (float*)   take((size_t)8192*1024*4);
  _Float16* wtf   = (_Float16*)take((size_t)32*1024*8*2);
  _Float16* wtb   = (_Float16*)take((size_t)32*1024*8*2);
  float*    hsf   = (float*)   take((size_t)64*128*256*4);
  float*    hsb   = (float*)   take((size_t)64*128*256*4);
  float*    iou   = (float*)   take((size_t)Nn*GG3*4);
  float*    um    = (float*)   take((size_t)Nn*GG3*4);
  float*    fm    = (float*)   take((size_t)Nn*HID*4);
  float*    cbuf  = (float*)   take((size_t)Nn*HID*4);
  ushort*   UTbf  = (ushort*)  take((size_t)1024*256*2);
  int*      tnlist= (int*)     take((size_t)64*128*4);
  int*      tlvloff=(int*)     take((size_t)64*130*4);
  int*      tnlv  = (int*)     take((size_t)64*4);
  int*      choff = (int*)     take((size_t)(Nn+1)*4);
  int*      chlist= (int*)     take((size_t)(E>0?E:1)*4);
  (void)ws_size; (void)n_in; (void)out_size;

  hipMemsetAsync(d_ws, 0, zero_end, stream);
  prep_kernel<<<1024, 256, 0, stream>>>(embed_ids, emb, xh, wihf, wtihf, wihb, wtihb,
                                        Wiou, wiouh, whhf, whhb, wtf, wtb, Uiou, Uf, UTbf);
  mfma_gemm2_kernel<<<dim3(64, 16), 256, 0, stream>>>(xh, wtihf, wtihb, bf, bb, xgf, xgb, 8192, 1024, 10);
  lstm_kernel<<<64, 512, 152576, stream>>>(xgf, xgb, wtf, wtb, lengths, hsf, hsb);
  mfma_gemm_iou_kernel<<<dim3((Nn + 127)/128, 6), 256, 0, stream>>>(tok_idx, hsf, hsb, wiouh, iou, Nn, GG3, 16);
  graph_kernel<<<65, 1024, 0, stream>>>(lengths, node_level, child_idx, parent_idx,
                                        tnlist, tlvloff, tnlv, choff, chlist, deg, E, Nn);
  tree_kernel<<<64, 512, 68096, stream>>>(tnlist, tlvloff, tnlv, choff, chlist, UTbf,
                                          biou, buf_, iou, um, fm, cbuf, hout);
}